// Round 5
// baseline (1595.355 us; speedup 1.0000x reference)
//
#include <hip/hip_runtime.h>
#include <hip/hip_bf16.h>
#include <cstdint>
#include <cstddef>

typedef __attribute__((ext_vector_type(4))) float f32x4;
typedef __attribute__((ext_vector_type(8))) short bf16x8;
typedef unsigned short u16;

#define DIN   256
#define DOUT  512
#define DXH   768
#define NJ    128
#define BATCH 1024

__device__ __forceinline__ u16 f2bf(float f) {
  union { float f; uint32_t u; } v; v.f = f;
  uint32_t r = v.u + 0x7fffu + ((v.u >> 16) & 1u);
  return (u16)(r >> 16);
}

// async global->LDS, 16B per lane; lds base must be wave-uniform
__device__ __forceinline__ void gl16(const u16* g, u16* l) {
  __builtin_amdgcn_global_load_lds(
      (const __attribute__((address_space(1))) void*)g,
      (__attribute__((address_space(3))) void*)l, 16, 0, 0);
}

// ---------------------------------------------------------------------------
// 128x128 GEMM tile (W / WL, K=128): round-4 version (3-deep, counted vmcnt).
// NOTE (r4 post-mortem): the read swizzle was proven a no-op on [128][32]
// tiles (bank = 16*(row&1)+4*chunk+j; any per-row chunk bijection keeps
// 8 lanes per 4-bank group = the structural minimum). Removed.
// ---------------------------------------------------------------------------
template <class Epi>
__device__ __forceinline__ void gemm128_bt(const u16* __restrict__ A, int lda,
                                           const u16* __restrict__ B, int ldb,
                                           int K, Epi epi) {
  __shared__ u16 As[3][128 * 32];
  __shared__ u16 Bs[3][128 * 32];
  const int tid  = threadIdx.x;
  const int lane = tid & 63;
  const int wave = tid >> 6;
  const int wm = wave >> 1, wn = wave & 1;
  const int lr = lane & 15, lk = lane >> 4;
  const int srow = lane >> 2;          // 0..15 within chunk
  const int scol = (lane & 3) * 8;     // element col within BK=32
  const int c0 = wave, c1 = wave + 4;

#define STAGE128(dA, dB, kk)                                                  \
  do {                                                                        \
    gl16(A + (size_t)(c0 * 16 + srow) * lda + (kk) + scol, (dA) + c0 * 512);  \
    gl16(A + (size_t)(c1 * 16 + srow) * lda + (kk) + scol, (dA) + c1 * 512);  \
    gl16(B + (size_t)(c0 * 16 + srow) * ldb + (kk) + scol, (dB) + c0 * 512);  \
    gl16(B + (size_t)(c1 * 16 + srow) * ldb + (kk) + scol, (dB) + c1 * 512);  \
  } while (0)

  f32x4 acc[4][4];
#pragma unroll
  for (int m = 0; m < 4; ++m)
#pragma unroll
    for (int n = 0; n < 4; ++n)
      acc[m][n] = (f32x4){0.f, 0.f, 0.f, 0.f};

  STAGE128(&As[0][0], &Bs[0][0], 0);
  STAGE128(&As[1][0], &Bs[1][0], 32);
  asm volatile("s_waitcnt vmcnt(4)" ::: "memory");
  __builtin_amdgcn_s_barrier();
  asm volatile("" ::: "memory");

  int cur = 0;
  const int nt = K >> 5;
  for (int t = 0; t < nt; ++t) {
    int s2 = cur + 2; if (s2 >= 3) s2 -= 3;
    if (t + 2 < nt) STAGE128(&As[s2][0], &Bs[s2][0], (t + 2) * 32);
    const u16* Asc = As[cur];
    const u16* Bsc = Bs[cur];
    bf16x8 af[4], bv[4];
#pragma unroll
    for (int m = 0; m < 4; ++m)
      af[m] = *(const bf16x8*)&Asc[(wm * 64 + m * 16 + lr) * 32 + lk * 8];
#pragma unroll
    for (int n = 0; n < 4; ++n)
      bv[n] = *(const bf16x8*)&Bsc[(wn * 64 + n * 16 + lr) * 32 + lk * 8];
#pragma unroll
    for (int m = 0; m < 4; ++m)
#pragma unroll
      for (int n = 0; n < 4; ++n)
        acc[m][n] = __builtin_amdgcn_mfma_f32_16x16x32_bf16(af[m], bv[n], acc[m][n], 0, 0, 0);
    if (t + 1 < nt) {
      if (t + 2 < nt) asm volatile("s_waitcnt vmcnt(4)" ::: "memory");
      else            asm volatile("s_waitcnt vmcnt(0)" ::: "memory");
      __builtin_amdgcn_s_barrier();
      asm volatile("" ::: "memory");
    }
    cur = (cur == 2) ? 0 : cur + 1;
  }
#undef STAGE128

#pragma unroll
  for (int m = 0; m < 4; ++m)
#pragma unroll
    for (int n = 0; n < 4; ++n)
#pragma unroll
      for (int r = 0; r < 4; ++r)
        epi(wm * 64 + m * 16 + lk * 4 + r, wn * 64 + n * 16 + lr, acc[m][n][r]);
}

// ---------------------------------------------------------------------------
// 128x256 GEMM tile, 4 waves, each wave owns a 64x128 sub-tile:
// per wave-tile 12 ds_read_b128 (4 A + 8 B) feed 32 MFMA (155 cyc) — double
// the MFMA density of the 128^2 tile at +50% reads. Round-0 control flow
// (verified best): single __syncthreads per K-tile, 2-deep LDS = 48KB ->
// 3 blocks/CU (the empirically achieved co-residency).
// C = A[128xK] * B[256xK]^T, bf16, K%32==0, blockDim=256.
// Rationale: cross-round fit MfmaUtil ~= waves/SIMD * mfma_cyc / ~1.5-1.9K
// path; raising mfma_cyc/wave-tile 77->155 is the strongest remaining lever.
// ---------------------------------------------------------------------------
template <class Epi>
__device__ __forceinline__ void gemm128x256_bt(const u16* __restrict__ A, int lda,
                                               const u16* __restrict__ B, int ldb,
                                               int K, Epi epi) {
  __shared__ u16 As[2][128 * 32];
  __shared__ u16 Bs[2][256 * 32];
  const int tid  = threadIdx.x;
  const int lane = tid & 63;
  const int wave = tid >> 6;            // 0..3
  const int wm = wave >> 1;             // 0..1: 64-row half of A
  const int wn = wave & 1;              // 0..1: 128-col half of B
  const int lr = lane & 15, lk = lane >> 4;
  const int srow = lane >> 2;           // 0..15 within 1KB chunk
  const int scol = (lane & 3) * 8;      // element col within BK=32

  // A: 8 chunks (128 rows), wave stages {wave, wave+4};
  // B: 16 chunks (256 rows), wave stages {wave, wave+4, wave+8, wave+12}.
#define STAGE(buf, kk)                                                        \
  do {                                                                        \
    gl16(A + (size_t)(wave * 16 + srow) * lda + (kk) + scol,                  \
         &As[buf][wave * 512]);                                               \
    gl16(A + (size_t)((wave + 4) * 16 + srow) * lda + (kk) + scol,            \
         &As[buf][(wave + 4) * 512]);                                         \
    _Pragma("unroll")                                                         \
    for (int g = 0; g < 4; ++g)                                               \
      gl16(B + (size_t)((wave + 4 * g) * 16 + srow) * ldb + (kk) + scol,      \
           &Bs[buf][(wave + 4 * g) * 512]);                                   \
  } while (0)

  f32x4 acc[4][8];
#pragma unroll
  for (int m = 0; m < 4; ++m)
#pragma unroll
    for (int n = 0; n < 8; ++n)
      acc[m][n] = (f32x4){0.f, 0.f, 0.f, 0.f};

  STAGE(0, 0);
  __syncthreads();
  int cur = 0;
  const int nt = K >> 5;
  for (int t = 0; t < nt; ++t) {
    if (t + 1 < nt) STAGE(cur ^ 1, (t + 1) * 32);   // prefetch overlaps MFMA
    const u16* Asc = As[cur];
    const u16* Bsc = Bs[cur];
    bf16x8 af[4], bv[8];
#pragma unroll
    for (int m = 0; m < 4; ++m)
      af[m] = *(const bf16x8*)&Asc[(wm * 64 + m * 16 + lr) * 32 + lk * 8];
#pragma unroll
    for (int n = 0; n < 8; ++n)
      bv[n] = *(const bf16x8*)&Bsc[(wn * 128 + n * 16 + lr) * 32 + lk * 8];
#pragma unroll
    for (int m = 0; m < 4; ++m)
#pragma unroll
      for (int n = 0; n < 8; ++n)
        acc[m][n] = __builtin_amdgcn_mfma_f32_16x16x32_bf16(af[m], bv[n], acc[m][n], 0, 0, 0);
    if (t + 1 < nt) { __syncthreads(); cur ^= 1; }  // drain stage + WAR
  }
#undef STAGE

#pragma unroll
  for (int m = 0; m < 4; ++m)
#pragma unroll
    for (int n = 0; n < 8; ++n)
#pragma unroll
      for (int r = 0; r < 4; ++r)
        epi(wm * 64 + m * 16 + lk * 4 + r, wn * 128 + n * 16 + lr, acc[m][n][r]);
}

// ---------------------------------------------------------------------------
// K0: weight prep — bf16 copies: Wzr=[Wz;Wr] [1024][768], Wh [512][768],
//     Wn [128][128]; bzr=[bz;br] fp32.
// ---------------------------------------------------------------------------
__global__ __launch_bounds__(256) void k_prepW(const float* __restrict__ Wz, const float* __restrict__ Wr,
                                               const float* __restrict__ Wh, const float* __restrict__ Wn,
                                               const float* __restrict__ bz, const float* __restrict__ br,
                                               u16* __restrict__ Wzrb, u16* __restrict__ Whb,
                                               u16* __restrict__ Wnb, float* __restrict__ bzr) {
  int i = blockIdx.x * 256 + threadIdx.x;
  if (i < DOUT * DXH) {
    Wzrb[i] = f2bf(Wz[i]);
    Wzrb[DOUT * DXH + i] = f2bf(Wr[i]);
    Whb[i] = f2bf(Wh[i]);
  }
  if (i < NJ * NJ) Wnb[i] = f2bf(Wn[i]);
  if (i < DOUT) { bzr[i] = bz[i]; bzr[DOUT + i] = br[i]; }
}

// ---------------------------------------------------------------------------
// K1: L = (A + I) / (D_i D_j + eps), D = sqrt(rowsum(A+I)); writes L and L^T.
// ---------------------------------------------------------------------------
__global__ __launch_bounds__(256) void k_prepL(const float* __restrict__ A,
                                               u16* __restrict__ Lb, u16* __restrict__ LbT) {
  __shared__ float Af[128 * 132];
  __shared__ float Dsh[128];
  const int b = blockIdx.x, tid = threadIdx.x;
  const float* Ab = A + (size_t)b * NJ * NJ;
#pragma unroll
  for (int i = tid; i < 4096; i += 256) {
    int row = i >> 5, col = (i & 31) * 4;
    float4 v = *(const float4*)(Ab + row * 128 + col);
    *(float4*)&Af[row * 132 + col] = v;
  }
  __syncthreads();
  if (tid < 128) {
    float s = 1.0f;
    for (int j = 0; j < 128; ++j) s += Af[tid * 132 + j];
    Dsh[tid] = sqrtf(s);
  }
  __syncthreads();
  const size_t base = (size_t)b * NJ * NJ;
  for (int i = tid; i < 16384; i += 256) {
    int r = i >> 7, c = i & 127;
    float num = Af[r * 132 + c] + (r == c ? 1.f : 0.f);
    Lb[base + i] = f2bf(num / (Dsh[r] * Dsh[c] + 1e-12f));
    float numt = Af[c * 132 + r] + (r == c ? 1.f : 0.f);
    LbT[base + i] = f2bf(numt / (Dsh[c] * Dsh[r] + 1e-12f));
  }
}

// ---------------------------------------------------------------------------
// Kx: XH[:, 0:256] = bf16(x)
// ---------------------------------------------------------------------------
__global__ __launch_bounds__(256) void k_prepXH(const float* __restrict__ x, u16* __restrict__ XHb) {
  size_t i = (size_t)blockIdx.x * 256 + threadIdx.x;
  size_t e = i * 4;
  size_t row = e >> 8;
  int c = (int)(e & 255);
  float4 v = *(const float4*)(x + e);
  u16 p[4] = {f2bf(v.x), f2bf(v.y), f2bf(v.z), f2bf(v.w)};
  *(uint2*)&XHb[row * DXH + c] = *(uint2*)p;
}

// ---------------------------------------------------------------------------
// K2: W = relu(L @ Wn^T + bn)          per-batch 128x128x128
// ---------------------------------------------------------------------------
__global__ __launch_bounds__(256) void k_gemm_W(const u16* __restrict__ Lb, const u16* __restrict__ Wnb,
                                                const float* __restrict__ bn, u16* __restrict__ Wb) {
  const int b = blockIdx.x;
  const u16* Ap = Lb + (size_t)b * NJ * NJ;
  u16* outp = Wb + (size_t)b * NJ * NJ;
  gemm128_bt(Ap, NJ, Wnb, NJ, NJ, [&](int r, int c, float v) {
    v += bn[c];
    outp[r * NJ + c] = f2bf(fmaxf(v, 0.f));
  });
}

// ---------------------------------------------------------------------------
// K3: WL = W @ L                        per-batch 128x128x128 (B = L^T)
// ---------------------------------------------------------------------------
__global__ __launch_bounds__(256) void k_gemm_WL(const u16* __restrict__ Wb, const u16* __restrict__ LbT,
                                                 u16* __restrict__ WLb) {
  const int b = blockIdx.x;
  u16* outp = WLb + (size_t)b * NJ * NJ;
  gemm128_bt(Wb + (size_t)b * NJ * NJ, NJ, LbT + (size_t)b * NJ * NJ, NJ, NJ,
             [&](int r, int c, float v) { outp[r * NJ + c] = f2bf(v); });
}

// ---------------------------------------------------------------------------
// K4: Y = WL @ X  (X = [x,h] transposed into LDS on the fly, fp32->bf16)
//     per-batch M=128, K=128, N=768 in 6 tiles of 128.
//     Grid pinned: 6 tiles of batch b on XCD b&7 (share WL panel in L2).
// ---------------------------------------------------------------------------
__global__ __launch_bounds__(256) void k_gemm_Y(const u16* __restrict__ WLb, const float* __restrict__ x,
                                                const float* __restrict__ h, u16* __restrict__ Yb) {
  __shared__ u16 As[2][128 * 32];
  __shared__ u16 Bt[128 * 136];   // [d][k], 272B rows
  const int tid  = threadIdx.x;
  const int lane = tid & 63;
  const int wave = tid >> 6;
  const int wm = wave >> 1, wn = wave & 1;
  const int lr = lane & 15, lk = lane >> 4;
  const int srow = lane >> 2, scol = (lane & 3) * 8;
  const int c0 = wave, c1 = wave + 4;

  const int xcd = blockIdx.x & 7, s = blockIdx.x >> 3;   // s in [0,768)
  const int tile = s % 6;
  const int b = ((s / 6) << 3) | xcd;
  const int d0 = tile * 128;
  const float* src; int sld;
  if (d0 < DIN) { src = x + (size_t)b * NJ * DIN + d0; sld = DIN; }
  else          { src = h + (size_t)b * NJ * DOUT + (d0 - DIN); sld = DOUT; }

  const u16* Ap = WLb + (size_t)b * NJ * NJ;
#define STAGE_A(buf, kk)                                                        \
  do {                                                                          \
    gl16(Ap + (size_t)(c0 * 16 + srow) * NJ + (kk) + scol, &As[buf][c0 * 512]); \
    gl16(Ap + (size_t)(c1 * 16 + srow) * NJ + (kk) + scol, &As[buf][c1 * 512]); \
  } while (0)

  STAGE_A(0, 0);

  // stage Bt[d][k] = X[k][d0+d]; pack k-pairs into u32 writes
#pragma unroll
  for (int it = 0; it < 32; ++it) {
    int task = it * 256 + tid;            // 8192 tasks = 128 d x 64 kpairs
    int d = task & 127, p = task >> 7;
    float v0 = src[(size_t)(2 * p) * sld + d];
    float v1 = src[(size_t)(2 * p + 1) * sld + d];
    uint32_t pk = (uint32_t)f2bf(v0) | ((uint32_t)f2bf(v1) << 16);
    *(uint32_t*)&Bt[d * 136 + 2 * p] = pk;
  }

  f32x4 acc[4][4];
#pragma unroll
  for (int m = 0; m < 4; ++m)
#pragma unroll
    for (int n = 0; n < 4; ++n)
      acc[m][n] = (f32x4){0.f, 0.f, 0.f, 0.f};

  __syncthreads();                       // Bt + As[0] visible
  int cur = 0;
  for (int t = 0; t < 4; ++t) {
    if (t < 3) STAGE_A(cur ^ 1, (t + 1) * 32);
    const u16* Asc = As[cur];
    const int k0 = t * 32;
    bf16x8 af[4], bv[4];
#pragma unroll
    for (int m = 0; m < 4; ++m)
      af[m] = *(const bf16x8*)&Asc[(wm * 64 + m * 16 + lr) * 32 + lk * 8];
#pragma unroll
    for (int n = 0; n < 4; ++n)
      bv[n] = *(const bf16x8*)&Bt[(wn * 64 + n * 16 + lr) * 136 + k0 + lk * 8];
#pragma unroll
    for (int m = 0; m < 4; ++m)
#pragma unroll
      for (int n = 0; n < 4; ++n)
        acc[m][n] = __builtin_amdgcn_mfma_f32_16x16x32_bf16(af[m], bv[n], acc[m][n], 0, 0, 0);
    if (t < 3) { __syncthreads(); cur ^= 1; }
  }
#undef STAGE_A

  u16* outp = Yb + (size_t)b * NJ * DXH + d0;
#pragma unroll
  for (int m = 0; m < 4; ++m)
#pragma unroll
    for (int n = 0; n < 4; ++n)
#pragma unroll
      for (int r = 0; r < 4; ++r)
        outp[(size_t)(wm * 64 + m * 16 + lk * 4 + r) * DXH + wn * 64 + n * 16 + lr] =
            f2bf(acc[m][n][r]);
}

// ---------------------------------------------------------------------------
// K5: [Z|R] = sigmoid(Y @ Wzr^T + bzr).  Z -> d_out (fp32, temp);
//     R -> XH[:,256:768] = bf16(h * R).
//     128x256 tiles: 4096 blocks; the 4 bn-blocks of a bm adjacent in
//     dispatch, pinned to XCD bm&7 (Y panel L2-resident).
// ---------------------------------------------------------------------------
__global__ __launch_bounds__(256) void k_gemm_ZR(const u16* __restrict__ Yb, const u16* __restrict__ Wzrb,
                                                 const float* __restrict__ bzr, const float* __restrict__ h,
                                                 float* __restrict__ outZ, u16* __restrict__ XHb) {
  const int xcd = blockIdx.x & 7, s = blockIdx.x >> 3;   // s in [0,512)
  const int bn = s & 3;
  const int bm = ((s >> 2) << 3) | xcd;                  // 0..1023
  gemm128x256_bt(Yb + (size_t)bm * 128 * DXH, DXH, Wzrb + (size_t)bn * 256 * DXH, DXH, DXH,
                 [&](int r, int c, float v) {
                   size_t row = (size_t)bm * 128 + r;
                   int col = bn * 256 + c;
                   v += bzr[col];
                   float sg = 1.f / (1.f + __expf(-v));
                   if (col < DOUT) {
                     outZ[row * DOUT + col] = sg;             // park Z in d_out
                   } else {
                     int o = col - DOUT;
                     XHb[row * DXH + DIN + o] = f2bf(sg * h[row * DOUT + o]);
                   }
                 });
}

// ---------------------------------------------------------------------------
// K6: H = tanh(XH @ Wh^T + bh); out = Z*h + (1-Z)*H   (Z read from d_out)
//     128x256 tiles: 2048 blocks; 2 bn-blocks per bm, pinned to XCD bm&7.
// ---------------------------------------------------------------------------
__global__ __launch_bounds__(256) void k_gemm_H(const u16* __restrict__ XHb, const u16* __restrict__ Whb,
                                                const float* __restrict__ bh, const float* __restrict__ h,
                                                float* __restrict__ outp) {
  const int xcd = blockIdx.x & 7, s = blockIdx.x >> 3;   // s in [0,256)
  const int bn = s & 1;
  const int bm = ((s >> 1) << 3) | xcd;                  // 0..1023
  gemm128x256_bt(XHb + (size_t)bm * 128 * DXH, DXH, Whb + (size_t)bn * 256 * DXH, DXH, DXH,
                 [&](int r, int c, float v) {
                   size_t row = (size_t)bm * 128 + r;
                   int col = bn * 256 + c;
                   float Hh = tanhf(v + bh[col]);
                   size_t idx = row * DOUT + col;
                   float z = outp[idx];
                   outp[idx] = z * h[idx] + (1.f - z) * Hh;
                 });
}

// ---------------------------------------------------------------------------
extern "C" void kernel_launch(void* const* d_in, const int* in_sizes, int n_in,
                              void* d_out, int out_size, void* d_ws, size_t ws_size,
                              hipStream_t stream) {
  const float* x  = (const float*)d_in[0];
  const float* h  = (const float*)d_in[1];
  const float* A  = (const float*)d_in[2];
  const float* Wz = (const float*)d_in[3];
  const float* bz = (const float*)d_in[4];
  const float* Wr = (const float*)d_in[5];
  const float* br = (const float*)d_in[6];
  const float* Wh = (const float*)d_in[7];
  const float* bh = (const float*)d_in[8];
  const float* Wn = (const float*)d_in[9];
  const float* bn = (const float*)d_in[10];
  float* out = (float*)d_out;
  char* ws = (char*)d_ws;

  // workspace layout (bytes)
  u16* Yb   = (u16*)(ws);                      // 201326592
  u16* XHb  = (u16*)(ws + 201326592);          // 201326592
  u16* Lb   = (u16*)(ws + 402653184);          // 33554432
  u16* LbT  = (u16*)(ws + 436207616);          // 33554432
  u16* Wb   = (u16*)(ws + 469762048);          // 33554432
  u16* WLb  = Lb;                              // alias: Lb dead after k_gemm_W
  u16* Wzrb = (u16*)(ws + 503316480);          // 1572864
  u16* Whb  = (u16*)(ws + 504889344);          // 786432
  u16* Wnb  = (u16*)(ws + 505675776);          // 32768
  float* bzr = (float*)(ws + 505708544);       // 4096

  k_prepW<<<dim3(1536), dim3(256), 0, stream>>>(Wz, Wr, Wh, Wn, bz, br, Wzrb, Whb, Wnb, bzr);
  k_prepL<<<dim3(BATCH), dim3(256), 0, stream>>>(A, Lb, LbT);
  k_prepXH<<<dim3(32768), dim3(256), 0, stream>>>(x, XHb);
  k_gemm_W<<<dim3(BATCH), dim3(256), 0, stream>>>(Lb, Wnb, bn, Wb);
  k_gemm_WL<<<dim3(BATCH), dim3(256), 0, stream>>>(Wb, LbT, WLb);
  k_gemm_Y<<<dim3(BATCH * 6), dim3(256), 0, stream>>>(WLb, x, h, Yb);
  k_gemm_ZR<<<dim3(1024 * 4), dim3(256), 0, stream>>>(Yb, Wzrb, bzr, h, out, XHb);
  k_gemm_H<<<dim3(1024 * 2), dim3(256), 0, stream>>>(XHb, Whb, bh, h, out);
}

// Round 7
// 970.627 us; speedup vs baseline: 1.6436x; 1.6436x over previous
//
#include <hip/hip_runtime.h>
#include <hip/hip_bf16.h>
#include <cstdint>
#include <cstddef>

typedef __attribute__((ext_vector_type(4))) float f32x4;
typedef __attribute__((ext_vector_type(8))) short bf16x8;
typedef unsigned short u16;

#define DIN   256
#define DOUT  512
#define DXH   768
#define NJ    128
#define BATCH 1024

__device__ __forceinline__ u16 f2bf(float f) {
  union { float f; uint32_t u; } v; v.f = f;
  uint32_t r = v.u + 0x7fffu + ((v.u >> 16) & 1u);
  return (u16)(r >> 16);
}

// async global->LDS, 16B per lane; lds base must be wave-uniform
__device__ __forceinline__ void gl16(const u16* g, u16* l) {
  __builtin_amdgcn_global_load_lds(
      (const __attribute__((address_space(1))) void*)g,
      (__attribute__((address_space(3))) void*)l, 16, 0, 0);
}

// ---------------------------------------------------------------------------
// 128x128 GEMM tile, BK=32, round-4 pipeline (3-deep LDS, counted vmcnt(4),
// one barrier per K-tile — best measured structure this session, 555 us ZR).
// LDS is HOISTED (caller passes smem, 24576 u16 = 48 KB) so one kernel can
// run two GEMM phases against the same buffers (k_gemm_H2).
// Epilogue callback: epi(m, n, rr, r, c, v) — (m,n,rr) are compile-time
// unrolled indices for register parking; (r,c) the local 128x128 coords.
// C = A[128xK] * B[128xK]^T, bf16, K%32==0, nt>=3, blockDim=256.
// ---------------------------------------------------------------------------
template <class Epi>
__device__ __forceinline__ void gemm128_bt(u16* __restrict__ smem,
                                           const u16* __restrict__ A, int lda,
                                           const u16* __restrict__ B, int ldb,
                                           int K, Epi epi) {
  const int tid  = threadIdx.x;
  const int lane = tid & 63;
  const int wave = tid >> 6;
  const int wm = wave >> 1, wn = wave & 1;
  const int lr = lane & 15, lk = lane >> 4;
  const int srow = lane >> 2;          // 0..15 within chunk
  const int scol = (lane & 3) * 8;     // element col within BK=32
  const int c0 = wave, c1 = wave + 4;
  u16* Asb = smem;                     // [3][4096]
  u16* Bsb = smem + 12288;             // [3][4096]

#define STAGE128(dA, dB, kk)                                                  \
  do {                                                                        \
    gl16(A + (size_t)(c0 * 16 + srow) * lda + (kk) + scol, (dA) + c0 * 512);  \
    gl16(A + (size_t)(c1 * 16 + srow) * lda + (kk) + scol, (dA) + c1 * 512);  \
    gl16(B + (size_t)(c0 * 16 + srow) * ldb + (kk) + scol, (dB) + c0 * 512);  \
    gl16(B + (size_t)(c1 * 16 + srow) * ldb + (kk) + scol, (dB) + c1 * 512);  \
  } while (0)

  f32x4 acc[4][4];
#pragma unroll
  for (int m = 0; m < 4; ++m)
#pragma unroll
    for (int n = 0; n < 4; ++n)
      acc[m][n] = (f32x4){0.f, 0.f, 0.f, 0.f};

  STAGE128(Asb, Bsb, 0);
  STAGE128(Asb + 4096, Bsb + 4096, 32);
  asm volatile("s_waitcnt vmcnt(4)" ::: "memory");
  __builtin_amdgcn_s_barrier();
  asm volatile("" ::: "memory");

  int cur = 0;
  const int nt = K >> 5;
  for (int t = 0; t < nt; ++t) {
    int s2 = cur + 2; if (s2 >= 3) s2 -= 3;
    if (t + 2 < nt) STAGE128(Asb + s2 * 4096, Bsb + s2 * 4096, (t + 2) * 32);
    const u16* Asc = Asb + cur * 4096;
    const u16* Bsc = Bsb + cur * 4096;
    bf16x8 af[4], bv[4];
#pragma unroll
    for (int m = 0; m < 4; ++m)
      af[m] = *(const bf16x8*)&Asc[(wm * 64 + m * 16 + lr) * 32 + lk * 8];
#pragma unroll
    for (int n = 0; n < 4; ++n)
      bv[n] = *(const bf16x8*)&Bsc[(wn * 64 + n * 16 + lr) * 32 + lk * 8];
#pragma unroll
    for (int m = 0; m < 4; ++m)
#pragma unroll
      for (int n = 0; n < 4; ++n)
        acc[m][n] = __builtin_amdgcn_mfma_f32_16x16x32_bf16(af[m], bv[n], acc[m][n], 0, 0, 0);
    if (t + 1 < nt) {
      if (t + 2 < nt) asm volatile("s_waitcnt vmcnt(4)" ::: "memory");
      else            asm volatile("s_waitcnt vmcnt(0)" ::: "memory");
      __builtin_amdgcn_s_barrier();
      asm volatile("" ::: "memory");
    }
    cur = (cur == 2) ? 0 : cur + 1;
  }
#undef STAGE128

#pragma unroll
  for (int m = 0; m < 4; ++m)
#pragma unroll
    for (int n = 0; n < 4; ++n)
#pragma unroll
      for (int rr = 0; rr < 4; ++rr)
        epi(m, n, rr, wm * 64 + m * 16 + lk * 4 + rr, wn * 64 + n * 16 + lr,
            acc[m][n][rr]);
}

// ---------------------------------------------------------------------------
// K0: weight prep — bf16 copies: Wzr=[Wz;Wr] [1024][768], Wh [512][768],
//     Wn [128][128]; bzr=[bz;br] fp32.
// ---------------------------------------------------------------------------
__global__ __launch_bounds__(256) void k_prepW(const float* __restrict__ Wz, const float* __restrict__ Wr,
                                               const float* __restrict__ Wh, const float* __restrict__ Wn,
                                               const float* __restrict__ bz, const float* __restrict__ br,
                                               u16* __restrict__ Wzrb, u16* __restrict__ Whb,
                                               u16* __restrict__ Wnb, float* __restrict__ bzr) {
  int i = blockIdx.x * 256 + threadIdx.x;
  if (i < DOUT * DXH) {
    Wzrb[i] = f2bf(Wz[i]);
    Wzrb[DOUT * DXH + i] = f2bf(Wr[i]);
    Whb[i] = f2bf(Wh[i]);
  }
  if (i < NJ * NJ) Wnb[i] = f2bf(Wn[i]);
  if (i < DOUT) { bzr[i] = bz[i]; bzr[DOUT + i] = br[i]; }
}

// ---------------------------------------------------------------------------
// K1: L = (A + I) / (D_i D_j + eps), D = sqrt(rowsum(A+I)); writes L and L^T.
//     Row-sum: 2 threads/row, float4 LDS reads.
// ---------------------------------------------------------------------------
__global__ __launch_bounds__(256) void k_prepL(const float* __restrict__ A,
                                               u16* __restrict__ Lb, u16* __restrict__ LbT) {
  __shared__ float Af[128 * 132];
  __shared__ float Psh[256];
  __shared__ float Dsh[128];
  const int b = blockIdx.x, tid = threadIdx.x;
  const float* Ab = A + (size_t)b * NJ * NJ;
#pragma unroll
  for (int i = tid; i < 4096; i += 256) {
    int row = i >> 5, col = (i & 31) * 4;
    float4 v = *(const float4*)(Ab + row * 128 + col);
    *(float4*)&Af[row * 132 + col] = v;
  }
  __syncthreads();
  {
    int row = tid >> 1, half = tid & 1;
    float s = half ? 0.f : 1.f;                  // self-loop +1 once per row
    const float* rp = &Af[row * 132 + half * 64];
#pragma unroll
    for (int j = 0; j < 64; j += 4) {
      float4 v4 = *(const float4*)(rp + j);
      s += v4.x + v4.y + v4.z + v4.w;
    }
    Psh[tid] = s;
  }
  __syncthreads();
  if (tid < 128) Dsh[tid] = sqrtf(Psh[2 * tid] + Psh[2 * tid + 1]);
  __syncthreads();
  const size_t base = (size_t)b * NJ * NJ;
  for (int i = tid; i < 16384; i += 256) {
    int r = i >> 7, c = i & 127;
    float num = Af[r * 132 + c] + (r == c ? 1.f : 0.f);
    Lb[base + i] = f2bf(num / (Dsh[r] * Dsh[c] + 1e-12f));
    float numt = Af[c * 132 + r] + (r == c ? 1.f : 0.f);
    LbT[base + i] = f2bf(numt / (Dsh[c] * Dsh[r] + 1e-12f));
  }
}

// ---------------------------------------------------------------------------
// Kx: XH[:, 0:256] = bf16(x)
// ---------------------------------------------------------------------------
__global__ __launch_bounds__(256) void k_prepXH(const float* __restrict__ x, u16* __restrict__ XHb) {
  size_t i = (size_t)blockIdx.x * 256 + threadIdx.x;
  size_t e = i * 4;
  size_t row = e >> 8;
  int c = (int)(e & 255);
  float4 v = *(const float4*)(x + e);
  u16 p[4] = {f2bf(v.x), f2bf(v.y), f2bf(v.z), f2bf(v.w)};
  *(uint2*)&XHb[row * DXH + c] = *(uint2*)p;
}

// ---------------------------------------------------------------------------
// K2: W = relu(L @ Wn^T + bn)          per-batch 128x128x128
// ---------------------------------------------------------------------------
__global__ __launch_bounds__(256) void k_gemm_W(const u16* __restrict__ Lb, const u16* __restrict__ Wnb,
                                                const float* __restrict__ bn, u16* __restrict__ Wb) {
  __shared__ u16 smem[24576];
  const int b = blockIdx.x;
  const u16* Ap = Lb + (size_t)b * NJ * NJ;
  u16* outp = Wb + (size_t)b * NJ * NJ;
  gemm128_bt(smem, Ap, NJ, Wnb, NJ, NJ, [&](int, int, int, int r, int c, float v) {
    v += bn[c];
    outp[r * NJ + c] = f2bf(fmaxf(v, 0.f));
  });
}

// ---------------------------------------------------------------------------
// K3: WL = W @ L                        per-batch 128x128x128 (B = L^T)
// ---------------------------------------------------------------------------
__global__ __launch_bounds__(256) void k_gemm_WL(const u16* __restrict__ Wb, const u16* __restrict__ LbT,
                                                 u16* __restrict__ WLb) {
  __shared__ u16 smem[24576];
  const int b = blockIdx.x;
  u16* outp = WLb + (size_t)b * NJ * NJ;
  gemm128_bt(smem, Wb + (size_t)b * NJ * NJ, NJ, LbT + (size_t)b * NJ * NJ, NJ, NJ,
             [&](int, int, int, int r, int c, float v) { outp[r * NJ + c] = f2bf(v); });
}

// ---------------------------------------------------------------------------
// K4: Y = WL @ X  (X = [x,h] transposed into LDS on the fly, fp32->bf16)
//     per-batch M=128, K=128, N=768 in 6 tiles of 128.
//     Grid pinned: 6 tiles of batch b on XCD b&7 (share WL panel in L2).
//     Bt staging float4-vectorized.
// ---------------------------------------------------------------------------
__global__ __launch_bounds__(256) void k_gemm_Y(const u16* __restrict__ WLb, const float* __restrict__ x,
                                                const float* __restrict__ h, u16* __restrict__ Yb) {
  __shared__ u16 As[2][128 * 32];
  __shared__ u16 Bt[128 * 136];   // [d][k], 272B rows
  const int tid  = threadIdx.x;
  const int lane = tid & 63;
  const int wave = tid >> 6;
  const int wm = wave >> 1, wn = wave & 1;
  const int lr = lane & 15, lk = lane >> 4;
  const int srow = lane >> 2, scol = (lane & 3) * 8;
  const int c0 = wave, c1 = wave + 4;

  const int xcd = blockIdx.x & 7, s = blockIdx.x >> 3;   // s in [0,768)
  const int tile = s % 6;
  const int b = ((s / 6) << 3) | xcd;
  const int d0 = tile * 128;
  const float* src; int sld;
  if (d0 < DIN) { src = x + (size_t)b * NJ * DIN + d0; sld = DIN; }
  else          { src = h + (size_t)b * NJ * DOUT + (d0 - DIN); sld = DOUT; }

  const u16* Ap = WLb + (size_t)b * NJ * NJ;
#define STAGE_A(buf, kk)                                                        \
  do {                                                                          \
    gl16(Ap + (size_t)(c0 * 16 + srow) * NJ + (kk) + scol, &As[buf][c0 * 512]); \
    gl16(Ap + (size_t)(c1 * 16 + srow) * NJ + (kk) + scol, &As[buf][c1 * 512]); \
  } while (0)

  STAGE_A(0, 0);

  // stage Bt[d][k] = X[k][d0+d]; float4 over d, pack k-pairs into u32
#pragma unroll
  for (int it = 0; it < 8; ++it) {
    int task = it * 256 + tid;            // 2048 tasks = 32 dq x 64 kpairs
    int dq = task & 31, p = task >> 5;
    const float* s0 = src + (size_t)(2 * p) * sld + dq * 4;
    const float* s1 = src + (size_t)(2 * p + 1) * sld + dq * 4;
    float4 v0 = *(const float4*)s0;
    float4 v1 = *(const float4*)s1;
    u16* bp = &Bt[(dq * 4) * 136 + 2 * p];
    *(uint32_t*)(bp)       = (uint32_t)f2bf(v0.x) | ((uint32_t)f2bf(v1.x) << 16);
    *(uint32_t*)(bp + 136) = (uint32_t)f2bf(v0.y) | ((uint32_t)f2bf(v1.y) << 16);
    *(uint32_t*)(bp + 272) = (uint32_t)f2bf(v0.z) | ((uint32_t)f2bf(v1.z) << 16);
    *(uint32_t*)(bp + 408) = (uint32_t)f2bf(v0.w) | ((uint32_t)f2bf(v1.w) << 16);
  }

  f32x4 acc[4][4];
#pragma unroll
  for (int m = 0; m < 4; ++m)
#pragma unroll
    for (int n = 0; n < 4; ++n)
      acc[m][n] = (f32x4){0.f, 0.f, 0.f, 0.f};

  __syncthreads();                       // Bt + As[0] visible
  int cur = 0;
  for (int t = 0; t < 4; ++t) {
    if (t < 3) STAGE_A(cur ^ 1, (t + 1) * 32);
    const u16* Asc = As[cur];
    const int k0 = t * 32;
    bf16x8 af[4], bv[4];
#pragma unroll
    for (int m = 0; m < 4; ++m)
      af[m] = *(const bf16x8*)&Asc[(wm * 64 + m * 16 + lr) * 32 + lk * 8];
#pragma unroll
    for (int n = 0; n < 4; ++n)
      bv[n] = *(const bf16x8*)&Bt[(wn * 64 + n * 16 + lr) * 136 + k0 + lk * 8];
#pragma unroll
    for (int m = 0; m < 4; ++m)
#pragma unroll
      for (int n = 0; n < 4; ++n)
        acc[m][n] = __builtin_amdgcn_mfma_f32_16x16x32_bf16(af[m], bv[n], acc[m][n], 0, 0, 0);
    if (t < 3) { __syncthreads(); cur ^= 1; }
  }
#undef STAGE_A

  u16* outp = Yb + (size_t)b * NJ * DXH + d0;
#pragma unroll
  for (int m = 0; m < 4; ++m)
#pragma unroll
    for (int n = 0; n < 4; ++n)
#pragma unroll
      for (int r = 0; r < 4; ++r)
        outp[(size_t)(wm * 64 + m * 16 + lk * 4 + r) * DXH + wn * 64 + n * 16 + lr] =
            f2bf(acc[m][n][r]);
}

// ---------------------------------------------------------------------------
// K5: R = sigmoid(Y @ Wr^T + br); XH[:,256:768] = bf16(h * R).
//     N=512 only (R half). 4096 blocks; 4 bn-blocks of a bm adjacent,
//     pinned to XCD bm&7 (Y panel L2-resident). Z is NOT computed here —
//     it is fused into k_gemm_H2 (never touches memory).
// ---------------------------------------------------------------------------
__global__ __launch_bounds__(256) void k_gemm_R(const u16* __restrict__ Yb, const u16* __restrict__ Wzrb,
                                                const float* __restrict__ bzr, const float* __restrict__ h,
                                                u16* __restrict__ XHb) {
  __shared__ u16 smem[24576];
  const int xcd = blockIdx.x & 7, s = blockIdx.x >> 3;   // s in [0,512)
  const int bn = s & 3;
  const int bm = ((s >> 2) << 3) | xcd;                  // 0..1023
  const u16* Bw = Wzrb + (size_t)(DOUT + bn * 128) * DXH;   // Wr rows
  gemm128_bt(smem, Yb + (size_t)bm * 128 * DXH, DXH, Bw, DXH, DXH,
             [&](int, int, int, int r, int c, float v) {
               size_t row = (size_t)bm * 128 + r;
               int col = bn * 128 + c;                   // 0..511 within R
               float sg = 1.f / (1.f + __expf(-(v + bzr[DOUT + col])));
               XHb[row * DXH + DIN + col] = f2bf(sg * h[row * DOUT + col]);
             });
}

// ---------------------------------------------------------------------------
// K6: fused Z+H: per 128x128 output block run TWO K=768 GEMMs over the same
//     LDS pipeline:  Z = sigmoid(Y @ Wz^T + bz)  -> parked in fp32 registers
//     (f32x4 zp[4][4] = 64 VGPRs; statically indexed — no scratch);
//     H = tanh(XH @ Wh^T + bh);  out = Z*h + (1-Z)*H.
//     Numerics now IDENTICAL to the r4 split path (fp32 z end-to-end) —
//     the r6 fp16 parking added ~2e-3 error and tripped the tolerance.
//     __launch_bounds__(256,3) = 3 blocks/CU pins the regalloc <=168 so the
//     48KB-LDS residency (3 blocks/CU) is not lost to VGPRs.
// ---------------------------------------------------------------------------
__global__ __launch_bounds__(256, 3) void k_gemm_H2(const u16* __restrict__ Yb, const u16* __restrict__ XHb,
                                                    const u16* __restrict__ Wzrb, const u16* __restrict__ Whb,
                                                    const float* __restrict__ bzr, const float* __restrict__ bh,
                                                    const float* __restrict__ h, float* __restrict__ outp) {
  __shared__ u16 smem[24576];
  const int xcd = blockIdx.x & 7, s = blockIdx.x >> 3;   // s in [0,512)
  const int bn = s & 3;
  const int bm = ((s >> 2) << 3) | xcd;                  // 0..1023

  f32x4 zp[4][4];                                        // 64 regs: fp32 Z park

  // phase 1: Z = sigmoid(Y @ Wz^T + bz), park in registers
  gemm128_bt(smem, Yb + (size_t)bm * 128 * DXH, DXH,
             Wzrb + (size_t)(bn * 128) * DXH, DXH, DXH,
             [&](int m, int n, int rr, int r, int c, float v) {
               zp[m][n][rr] = 1.f / (1.f + __expf(-(v + bzr[bn * 128 + c])));
             });
  __syncthreads();

  // phase 2: H = tanh(XH @ Wh^T + bh); combine with parked Z
  gemm128_bt(smem, XHb + (size_t)bm * 128 * DXH, DXH,
             Whb + (size_t)(bn * 128) * DXH, DXH, DXH,
             [&](int m, int n, int rr, int r, int c, float v) {
               size_t row = (size_t)bm * 128 + r;
               int col = bn * 128 + c;
               float Hh = tanhf(v + bh[col]);
               float z = zp[m][n][rr];
               size_t idx = row * DOUT + col;
               float hv = h[idx];
               outp[idx] = z * hv + (1.f - z) * Hh;
             });
}

// ---------------------------------------------------------------------------
extern "C" void kernel_launch(void* const* d_in, const int* in_sizes, int n_in,
                              void* d_out, int out_size, void* d_ws, size_t ws_size,
                              hipStream_t stream) {
  const float* x  = (const float*)d_in[0];
  const float* h  = (const float*)d_in[1];
  const float* A  = (const float*)d_in[2];
  const float* Wz = (const float*)d_in[3];
  const float* bz = (const float*)d_in[4];
  const float* Wr = (const float*)d_in[5];
  const float* br = (const float*)d_in[6];
  const float* Wh = (const float*)d_in[7];
  const float* bh = (const float*)d_in[8];
  const float* Wn = (const float*)d_in[9];
  const float* bn = (const float*)d_in[10];
  float* out = (float*)d_out;
  char* ws = (char*)d_ws;

  // workspace layout (bytes)
  u16* Yb   = (u16*)(ws);                      // 201326592
  u16* XHb  = (u16*)(ws + 201326592);          // 201326592
  u16* Lb   = (u16*)(ws + 402653184);          // 33554432
  u16* LbT  = (u16*)(ws + 436207616);          // 33554432
  u16* Wb   = (u16*)(ws + 469762048);          // 33554432
  u16* WLb  = Lb;                              // alias: Lb dead after k_gemm_W
  u16* Wzrb = (u16*)(ws + 503316480);          // 1572864
  u16* Whb  = (u16*)(ws + 504889344);          // 786432
  u16* Wnb  = (u16*)(ws + 505675776);          // 32768
  float* bzr = (float*)(ws + 505708544);       // 4096

  k_prepW<<<dim3(1536), dim3(256), 0, stream>>>(Wz, Wr, Wh, Wn, bz, br, Wzrb, Whb, Wnb, bzr);
  k_prepL<<<dim3(BATCH), dim3(256), 0, stream>>>(A, Lb, LbT);
  k_prepXH<<<dim3(32768), dim3(256), 0, stream>>>(x, XHb);
  k_gemm_W<<<dim3(BATCH), dim3(256), 0, stream>>>(Lb, Wnb, bn, Wb);
  k_gemm_WL<<<dim3(BATCH), dim3(256), 0, stream>>>(Wb, LbT, WLb);
  k_gemm_Y<<<dim3(BATCH * 6), dim3(256), 0, stream>>>(WLb, x, h, Yb);
  k_gemm_R<<<dim3(1024 * 4), dim3(256), 0, stream>>>(Yb, Wzrb, bzr, h, XHb);
  k_gemm_H2<<<dim3(1024 * 4), dim3(256), 0, stream>>>(Yb, XHb, Wzrb, Whb, bzr, bh, h, out);
}